// Round 14
// baseline (153.342 us; speedup 1.0000x reference)
//
#include <hip/hip_runtime.h>
#include <math.h>

typedef __bf16 bf16_t;
typedef bf16_t bf16x4 __attribute__((ext_vector_type(4)));
typedef bf16_t bf16x8 __attribute__((ext_vector_type(8)));
typedef float  f32x4  __attribute__((ext_vector_type(4)));

__device__ __forceinline__ float softplus_f(float x) {
    return (x > 20.f) ? x : log1pf(expf(x));
}

__device__ __forceinline__ float fast_rcp(float x) {
#if __has_builtin(__builtin_amdgcn_rcpf)
    return __builtin_amdgcn_rcpf(x);
#else
    return 1.0f / x;
#endif
}

// ---------------- prep: z<8 transpose+convert weights, z==8 convert activations ----------------
struct PrepArgs { const float* src[8]; const float* mu; const float* var; };

__global__ __launch_bounds__(256) void prep_kernel(PrepArgs pa, bf16_t* __restrict__ wtbase,
                                                   bf16_t* __restrict__ dmu, bf16_t* __restrict__ dvar) {
    const int t = threadIdx.x;
    if (blockIdx.z == 8) {
        const int gid = (blockIdx.y * 16 + blockIdx.x) * 256 + t;   // 0..65535
        const float* s; bf16_t* d; int off;
        if (gid < 32768) { s = pa.mu;  d = dmu;  off = gid * 8; }
        else             { s = pa.var; d = dvar; off = (gid - 32768) * 8; }
        float4 v0 = *(const float4*)(s + off);
        float4 v1 = *(const float4*)(s + off + 4);
        bf16x8 o;
        o[0] = (bf16_t)v0.x; o[1] = (bf16_t)v0.y; o[2] = (bf16_t)v0.z; o[3] = (bf16_t)v0.w;
        o[4] = (bf16_t)v1.x; o[5] = (bf16_t)v1.y; o[6] = (bf16_t)v1.z; o[7] = (bf16_t)v1.w;
        *(bf16x8*)(d + off) = o;
        return;
    }
    const int kt = blockIdx.x, nt = blockIdx.y, wm = blockIdx.z;
    const float* __restrict__ W = pa.src[wm];
    bf16_t* __restrict__ Wt = wtbase + (size_t)wm * 1048576;
    __shared__ bf16_t Ts[64][72];
    const int r0 = t >> 4, c4 = (t & 15) * 4;
#pragma unroll
    for (int rep = 0; rep < 4; ++rep) {
        const int r = r0 + rep * 16;
        const float4 v = *(const float4*)&W[(size_t)(kt * 64 + r) * 1024 + nt * 64 + c4];
        Ts[c4 + 0][r] = (bf16_t)v.x;
        Ts[c4 + 1][r] = (bf16_t)v.y;
        Ts[c4 + 2][r] = (bf16_t)v.z;
        Ts[c4 + 3][r] = (bf16_t)v.w;
    }
    __syncthreads();
#pragma unroll
    for (int rep = 0; rep < 2; ++rep) {
        const int chunk = t + rep * 256;
        const int n = chunk >> 3, kc = (chunk & 7) * 8;
        bf16x8 v = *(const bf16x8*)&Ts[n][kc];
        *(bf16x8*)&Wt[(size_t)(nt * 64 + n) * 1024 + kt * 64 + kc] = v;
    }
}

// ---------------- gemm tile helper: 64x64 split-K + reg prefetch; returns pre-bias sums ----------------
__device__ __forceinline__ void gemm_tile64(const bf16_t* __restrict__ A,
                                            const bf16_t* __restrict__ Wt,
                                            int m_base, int n_base,
                                            unsigned char* smem_raw, int t, f32x4 out[4]) {
    __syncthreads();   // LDS reuse safety (entry barrier; harmless on first call)
    bf16_t* stage = (bf16_t*)smem_raw;
    float*  Cr    = (float*)smem_raw;

    const int lane = t & 63;
    const int w = t >> 6;
    bf16_t* As = stage + w * 9216;
    bf16_t* Bs = As + 4608;

    const int r8 = lane >> 3, kb = lane & 7;
    const int fr = lane & 15, fq = lane >> 4, fk = fq * 8;

    const bf16_t* Ab = A  + (size_t)m_base * 1024 + w * 256 + kb * 8;
    const bf16_t* Bb = Wt + (size_t)n_base * 1024 + w * 256 + kb * 8;

    f32x4 acc[4][4] = {};

    bf16x8 pa[8], pb[8];
#pragma unroll
    for (int i = 0; i < 8; ++i) {
        pa[i] = *(const bf16x8*)(Ab + (size_t)(i * 8 + r8) * 1024);
        pb[i] = *(const bf16x8*)(Bb + (size_t)(i * 8 + r8) * 1024);
    }

#pragma unroll
    for (int s = 0; s < 4; ++s) {
#pragma unroll
        for (int i = 0; i < 8; ++i) {
            *(bf16x8*)&As[(i * 8 + r8) * 72 + kb * 8] = pa[i];
            *(bf16x8*)&Bs[(i * 8 + r8) * 72 + kb * 8] = pb[i];
        }
        if (s < 3) {
            const int off = (s + 1) * 64;
#pragma unroll
            for (int i = 0; i < 8; ++i) {
                pa[i] = *(const bf16x8*)(Ab + (size_t)(i * 8 + r8) * 1024 + off);
                pb[i] = *(const bf16x8*)(Bb + (size_t)(i * 8 + r8) * 1024 + off);
            }
        }
#pragma unroll
        for (int kh = 0; kh < 2; ++kh) {
            bf16x8 aF[4], bF[4];
#pragma unroll
            for (int i = 0; i < 4; ++i)
                aF[i] = *(const bf16x8*)&As[(i * 16 + fr) * 72 + kh * 32 + fk];
#pragma unroll
            for (int j = 0; j < 4; ++j)
                bF[j] = *(const bf16x8*)&Bs[(j * 16 + fr) * 72 + kh * 32 + fk];
#pragma unroll
            for (int i = 0; i < 4; ++i)
#pragma unroll
                for (int j = 0; j < 4; ++j)
                    acc[i][j] = __builtin_amdgcn_mfma_f32_16x16x32_bf16(aF[i], bF[j], acc[i][j], 0, 0, 0);
        }
    }

    __syncthreads();
    {
        float* Crw = Cr + w * 4352;
        const int orow = fq * 4;
#pragma unroll
        for (int i = 0; i < 4; ++i)
#pragma unroll
            for (int j = 0; j < 4; ++j)
#pragma unroll
                for (int rr = 0; rr < 4; ++rr)
                    Crw[(i * 16 + orow + rr) * 68 + j * 16 + fr] = acc[i][j][rr];
    }
    __syncthreads();

    const int cc = (t & 15) * 4;
#pragma unroll
    for (int i = 0; i < 4; ++i) {
        const int row = (t >> 4) + i * 16;
        f32x4 s0 = *(const f32x4*)&Cr[0 * 4352 + row * 68 + cc];
        f32x4 s1 = *(const f32x4*)&Cr[1 * 4352 + row * 68 + cc];
        f32x4 s2 = *(const f32x4*)&Cr[2 * 4352 + row * 68 + cc];
        f32x4 s3 = *(const f32x4*)&Cr[3 * 4352 + row * 68 + cc];
        out[i] = (s0 + s1) + (s2 + s3);
    }
}

// ---------------- gemm kernel: normal z-slots + fused-K slot (emits Gbf + cvec) ----------------
struct GemmArgs {
    const bf16_t* A[6];
    const bf16_t* Wt[6];
    const float*  bias[6];
    float*        dst[6];
    int           splus[6];
    int           fused[6];
    const bf16_t* A2[6];
    const bf16_t* Wt2[6];
    const float*  bias2[6];
    bf16_t* Gbf;
    float*  cvec;
};

__global__ __launch_bounds__(256, 2) void gemm_splitk(GemmArgs args) {
    const int z = blockIdx.z;
    const int n_base = blockIdx.x * 64;
    const int m_base = blockIdx.y * 64;

    __shared__ __align__(16) unsigned char smem_raw[73728];
    const int t = threadIdx.x;
    const int cc = (t & 15) * 4;

    if (!args.fused[z]) {
        f32x4 out[4];
        gemm_tile64(args.A[z], args.Wt[z], m_base, n_base, smem_raw, t, out);
        const int sp = args.splus[z];
        float* __restrict__ dst = args.dst[z];
        f32x4 bv4 = *(const f32x4*)&args.bias[z][n_base + cc];
#pragma unroll
        for (int i = 0; i < 4; ++i) {
            const int row = (t >> 4) + i * 16;
            f32x4 v = out[i] + bv4;
            if (sp) {
                v[0] = softplus_f(v[0]); v[1] = softplus_f(v[1]);
                v[2] = softplus_f(v[2]); v[3] = softplus_f(v[3]);
            }
            *(f32x4*)&dst[(size_t)(m_base + row) * 1024 + n_base + cc] = v;
        }
        return;
    }

    // fused-K: pass 1 = Km (A, Wt, bias), pass 2 = Kv (A2, Wt2, bias2, softplus)
    const int h = blockIdx.x;                 // 64 cols == exactly one head
    f32x4 km4[4], kv4[4];
    {
        f32x4 out[4];
        gemm_tile64(args.A[z], args.Wt[z], m_base, n_base, smem_raw, t, out);
        f32x4 b1 = *(const f32x4*)&args.bias[z][n_base + cc];
#pragma unroll
        for (int i = 0; i < 4; ++i) km4[i] = out[i] + b1;
    }
    {
        f32x4 out[4];
        gemm_tile64(args.A2[z], args.Wt2[z], m_base, n_base, smem_raw, t, out);
        f32x4 b2 = *(const f32x4*)&args.bias2[z][n_base + cc];
#pragma unroll
        for (int i = 0; i < 4; ++i) {
            f32x4 v = out[i] + b2;
            kv4[i][0] = softplus_f(v[0]); kv4[i][1] = softplus_f(v[1]);
            kv4[i][2] = softplus_f(v[2]); kv4[i][3] = softplus_f(v[3]);
        }
    }
    __syncthreads();   // all Cr reads done; reuse LDS for cvec partials
    float* part = (float*)smem_raw;           // [64][16]
#pragma unroll
    for (int i = 0; i < 4; ++i) {
        const int row = (t >> 4) + i * 16;
        bf16x4 o1, o2;
        float cp = 0.f;
#pragma unroll
        for (int e = 0; e < 4; ++e) {
            const float kv = kv4[i][e];
            const float km = km4[i][e];
            const float r = 0.5f * fast_rcp(kv);
            o1[e] = (bf16_t)r;
            o2[e] = (bf16_t)(-2.f * km * r);
            cp += km * km * r + 0.5f * __logf(kv);
        }
        bf16_t* grow = args.Gbf + ((size_t)(h * 256 + m_base + row)) * 128;
        *(bf16x4*)&grow[cc]      = o1;
        *(bf16x4*)&grow[64 + cc] = o2;
        part[row * 16 + (t & 15)] = cp;
    }
    __syncthreads();
    if (t < 64) {
        float s = 0.f;
#pragma unroll
        for (int j = 0; j < 16; ++j) s += part[t * 16 + j];
        args.cvec[h * 256 + m_base + t] = s;
    }
}

// ---------------- attn_v7: 512 threads (8 waves), MFMA scores + MFMA PV (R13-verified) ----------------
#define OFF_VM   0
#define OFF_VV   36864
#define OFF_FS   73728
#define OFF_SC   82176
#define OFF_PHI  98816
#define OFF_PLO  107264
#define OFF_P2H  115712
#define OFF_P2L  124160
#define ATTN_SMEM 132608

__global__ __launch_bounds__(512) void attn_v7(const float* __restrict__ Qm,
                                               const float* __restrict__ Qv,
                                               const bf16_t* __restrict__ Gbf,
                                               const float* __restrict__ cvec,
                                               const float* __restrict__ Vm,
                                               const float* __restrict__ Vv,
                                               bf16_t* __restrict__ Omu,
                                               bf16_t* __restrict__ Ovar) {
    __shared__ __align__(16) unsigned char smem[ATTN_SMEM];
    bf16_t* Vsm = (bf16_t*)(smem + OFF_VM);
    bf16_t* Vsv = (bf16_t*)(smem + OFF_VV);
    float*  Fs  = (float*)(smem + OFF_FS);
    float*  Sc  = (float*)(smem + OFF_SC);
    bf16_t* Phi = (bf16_t*)(smem + OFF_PHI);
    bf16_t* Plo = (bf16_t*)(smem + OFF_PLO);
    bf16_t* P2h = (bf16_t*)(smem + OFF_P2H);
    bf16_t* P2l = (bf16_t*)(smem + OFF_P2L);

    const int qt = blockIdx.x, h = blockIdx.y;
    const int t = threadIdx.x, w = t >> 6, lane = t & 63;
    const int fr = lane & 15, fq = lane >> 4;
    const int n0 = w * 32;

    const bf16_t* gB = Gbf + ((size_t)(h * 256 + n0 + fr)) * 128 + fq * 8;

    bf16x8 bcur[4];
#pragma unroll
    for (int ks = 0; ks < 4; ++ks) bcur[ks] = *(const bf16x8*)(gB + ks * 32);

    if (t < 256) {
        const int r = t >> 4, c = t & 15;
        f32x4 qm = *(const f32x4*)(Qm + (size_t)(qt * 16 + r) * 1024 + h * 64 + c * 4);
        f32x4 qv = *(const f32x4*)(Qv + (size_t)(qt * 16 + r) * 1024 + h * 64 + c * 4);
        *(f32x4*)&Fs[r * 132 + c * 4]      = qm * qm + qv;
        *(f32x4*)&Fs[r * 132 + 64 + c * 4] = qm;
    }
    __syncthreads();

    bf16x8 ahi[4], alo[4];
#pragma unroll
    for (int ks = 0; ks < 4; ++ks) {
        f32x4 f0 = *(const f32x4*)&Fs[fr * 132 + ks * 32 + fq * 8];
        f32x4 f1 = *(const f32x4*)&Fs[fr * 132 + ks * 32 + fq * 8 + 4];
#pragma unroll
        for (int e = 0; e < 4; ++e) {
            bf16_t hb = (bf16_t)f0[e];
            ahi[ks][e] = hb; alo[ks][e] = (bf16_t)(f0[e] - (float)hb);
            bf16_t hb2 = (bf16_t)f1[e];
            ahi[ks][e + 4] = hb2; alo[ks][e + 4] = (bf16_t)(f1[e] - (float)hb2);
        }
    }

    const int tm = t & 255;
    const int vk = tm >> 2, vpart = tm & 3;
    const float* Vsrc = (t >= 256) ? Vv : Vm;
    bf16_t*      Vdst = (t >= 256) ? Vsv : Vsm;

#pragma unroll
    for (int nt = 0; nt < 2; ++nt) {
        const int ra = vk + (2 * nt) * 64;
        const int rb = vk + (2 * nt + 1) * 64;
        const float* vsa = Vsrc + (size_t)ra * 1024 + h * 64 + vpart * 16;
        const float* vsb = Vsrc + (size_t)rb * 1024 + h * 64 + vpart * 16;
        f32x4 va0 = *(const f32x4*)(vsa),     va1 = *(const f32x4*)(vsa + 4);
        f32x4 va2 = *(const f32x4*)(vsa + 8), va3 = *(const f32x4*)(vsa + 12);
        f32x4 vb0 = *(const f32x4*)(vsb),     vb1 = *(const f32x4*)(vsb + 4);
        f32x4 vb2 = *(const f32x4*)(vsb + 8), vb3 = *(const f32x4*)(vsb + 12);

        bf16x8 bnxt[4];
        if (nt < 1) {
#pragma unroll
            for (int ks = 0; ks < 4; ++ks)
                bnxt[ks] = *(const bf16x8*)(gB + 2048 + ks * 32);
        }

        f32x4 acc = {0.f, 0.f, 0.f, 0.f};
#pragma unroll
        for (int ks = 0; ks < 4; ++ks) {
            acc = __builtin_amdgcn_mfma_f32_16x16x32_bf16(ahi[ks], bcur[ks], acc, 0, 0, 0);
            acc = __builtin_amdgcn_mfma_f32_16x16x32_bf16(alo[ks], bcur[ks], acc, 0, 0, 0);
        }

        {
            bf16_t* da = Vdst + ra * 72 + vpart * 16;
            bf16_t* db = Vdst + rb * 72 + vpart * 16;
            bf16x8 o0, o1;
            o0[0]=(bf16_t)va0[0]; o0[1]=(bf16_t)va0[1]; o0[2]=(bf16_t)va0[2]; o0[3]=(bf16_t)va0[3];
            o0[4]=(bf16_t)va1[0]; o0[5]=(bf16_t)va1[1]; o0[6]=(bf16_t)va1[2]; o0[7]=(bf16_t)va1[3];
            o1[0]=(bf16_t)va2[0]; o1[1]=(bf16_t)va2[1]; o1[2]=(bf16_t)va2[2]; o1[3]=(bf16_t)va2[3];
            o1[4]=(bf16_t)va3[0]; o1[5]=(bf16_t)va3[1]; o1[6]=(bf16_t)va3[2]; o1[7]=(bf16_t)va3[3];
            *(bf16x8*)(da)     = o0;
            *(bf16x8*)(da + 8) = o1;
            o0[0]=(bf16_t)vb0[0]; o0[1]=(bf16_t)vb0[1]; o0[2]=(bf16_t)vb0[2]; o0[3]=(bf16_t)vb0[3];
            o0[4]=(bf16_t)vb1[0]; o0[5]=(bf16_t)vb1[1]; o0[6]=(bf16_t)vb1[2]; o0[7]=(bf16_t)vb1[3];
            o1[0]=(bf16_t)vb2[0]; o1[1]=(bf16_t)vb2[1]; o1[2]=(bf16_t)vb2[2]; o1[3]=(bf16_t)vb2[3];
            o1[4]=(bf16_t)vb3[0]; o1[5]=(bf16_t)vb3[1]; o1[6]=(bf16_t)vb3[2]; o1[7]=(bf16_t)vb3[3];
            *(bf16x8*)(db)     = o0;
            *(bf16x8*)(db + 8) = o1;
        }

        const float cv = cvec[h * 256 + n0 + nt * 16 + fr];
        f32x4 lg = (acc + cv) * (-0.125f);
#pragma unroll
        for (int reg = 0; reg < 4; ++reg)
            Sc[(fq * 4 + reg) * 260 + n0 + nt * 16 + fr] = lg[reg];

#pragma unroll
        for (int ks = 0; ks < 4; ++ks) bcur[ks] = bnxt[ks];
    }
    __syncthreads();

    const int fw = w * 2;
    f32x4 sr[2];
#pragma unroll
    for (int r = 0; r < 2; ++r)
        sr[r] = *(const f32x4*)&Sc[(fw + r) * 260 + lane * 4];
#pragma unroll
    for (int r = 0; r < 2; ++r) {
        f32x4 s = sr[r];
        float mloc = fmaxf(fmaxf(s[0], s[1]), fmaxf(s[2], s[3]));
#pragma unroll
        for (int off = 32; off > 0; off >>= 1)
            mloc = fmaxf(mloc, __shfl_xor(mloc, off, 64));
        s[0] = __expf(s[0] - mloc); s[1] = __expf(s[1] - mloc);
        s[2] = __expf(s[2] - mloc); s[3] = __expf(s[3] - mloc);
        float sl = (s[0] + s[1]) + (s[2] + s[3]);
#pragma unroll
        for (int off = 32; off > 0; off >>= 1)
            sl += __shfl_xor(sl, off, 64);
        sr[r] = s * fast_rcp(sl);
    }

#pragma unroll
    for (int r = 0; r < 2; ++r) {
        bf16x4 phi, plo, p2hi, p2lo;
#pragma unroll
        for (int e = 0; e < 4; ++e) {
            const float p = sr[r][e];
            const bf16_t hb = (bf16_t)p;
            phi[e] = hb; plo[e] = (bf16_t)(p - (float)hb);
            const float p2 = p * p;
            const bf16_t h2 = (bf16_t)p2;
            p2hi[e] = h2; p2lo[e] = (bf16_t)(p2 - (float)h2);
        }
        const int row = fw + r;
        *(bf16x4*)&Phi[row * 264 + lane * 4] = phi;
        *(bf16x4*)&Plo[row * 264 + lane * 4] = plo;
        *(bf16x4*)&P2h[row * 264 + lane * 4] = p2hi;
        *(bf16x4*)&P2l[row * 264 + lane * 4] = p2lo;
    }
    __syncthreads();

    const int tile = w & 3;
    const int isvar = w >> 2;
    const bf16_t* Pa = isvar ? P2h : Phi;
    const bf16_t* Pb = isvar ? P2l : Plo;
    const bf16_t* Vs = isvar ? Vsv : Vsm;
    f32x4 accp = {0.f, 0.f, 0.f, 0.f};
#pragma unroll
    for (int k0 = 0; k0 < 256; k0 += 32) {
        const int ka = k0 + fq * 8;
        bf16x8 a1 = *(const bf16x8*)&Pa[fr * 264 + ka];
        bf16x8 a2 = *(const bf16x8*)&Pb[fr * 264 + ka];
        bf16x8 bfr;
#pragma unroll
        for (int j = 0; j < 8; ++j)
            bfr[j] = Vs[(ka + j) * 72 + tile * 16 + fr];
        accp = __builtin_amdgcn_mfma_f32_16x16x32_bf16(a1, bfr, accp, 0, 0, 0);
        accp = __builtin_amdgcn_mfma_f32_16x16x32_bf16(a2, bfr, accp, 0, 0, 0);
    }

    bf16_t* Out = isvar ? Ovar : Omu;
#pragma unroll
    for (int reg = 0; reg < 4; ++reg) {
        const int qg = qt * 16 + fq * 4 + reg;
        const size_t ob = (size_t)qg * 1024 + h * 64 + tile * 16 + fr;
        Out[ob] = (bf16_t)accp[reg];
    }
}

// ---------------- launch ----------------
extern "C" void kernel_launch(void* const* d_in, const int* in_sizes, int n_in,
                              void* d_out, int out_size, void* d_ws, size_t ws_size,
                              hipStream_t stream) {
    const float* mu  = (const float*)d_in[0];
    const float* var = (const float*)d_in[1];

    uint8_t* ws = (uint8_t*)d_ws;
    bf16_t* Abf_mu  = (bf16_t*)(ws);                              // 512 KB
    bf16_t* Abf_var = (bf16_t*)(ws + (512u << 10));               // 512 KB
    bf16_t* WtB     = (bf16_t*)(ws + (1u << 20));                 // 8 x 2 MB
    float*  Proj    = (float*)(ws + (17u << 20));                 // Qm,Qv,-,-,Vm,Vv (1 MB each)
    bf16_t* Obf_mu  = (bf16_t*)(ws + (23u << 20));                // 512 KB
    bf16_t* Obf_var = (bf16_t*)(ws + (23u << 20) + (512u << 10)); // 512 KB
    bf16_t* Gbf     = (bf16_t*)(ws + (24u << 20));                // 1 MB
    float*  cvec    = (float*)(ws + (25u << 20));                 // 16 KB

    PrepArgs pa;
    for (int i = 0; i < 8; ++i) pa.src[i] = (const float*)d_in[2 + 2 * i];
    pa.mu = mu; pa.var = var;
    prep_kernel<<<dim3(16, 16, 9), 256, 0, stream>>>(pa, WtB, Abf_mu, Abf_var);

    // K1: z0=Qm, z1=Qv, z2=Vm, z3=Vv, z4=fused-K (Km+Kv -> Gbf, cvec)
    GemmArgs g1 = {};
    g1.Gbf = Gbf; g1.cvec = cvec;
    // z0 Qm
    g1.A[0] = Abf_mu;  g1.Wt[0] = WtB + 0 * 1048576; g1.bias[0] = (const float*)d_in[3];
    g1.dst[0] = Proj;                 g1.splus[0] = 0; g1.fused[0] = 0;
    // z1 Qv
    g1.A[1] = Abf_var; g1.Wt[1] = WtB + 1 * 1048576; g1.bias[1] = (const float*)d_in[5];
    g1.dst[1] = Proj + 262144;        g1.splus[1] = 1; g1.fused[1] = 0;
    // z2 Vm
    g1.A[2] = Abf_mu;  g1.Wt[2] = WtB + 4 * 1048576; g1.bias[2] = (const float*)d_in[11];
    g1.dst[2] = Proj + 4 * 262144;    g1.splus[2] = 0; g1.fused[2] = 0;
    // z3 Vv
    g1.A[3] = Abf_var; g1.Wt[3] = WtB + 5 * 1048576; g1.bias[3] = (const float*)d_in[13];
    g1.dst[3] = Proj + 5 * 262144;    g1.splus[3] = 1; g1.fused[3] = 0;
    // z4 fused K: pass1 Km (wk_mu), pass2 Kv (wk_var)
    g1.A[4]  = Abf_mu;  g1.Wt[4]  = WtB + 2 * 1048576; g1.bias[4]  = (const float*)d_in[7];
    g1.A2[4] = Abf_var; g1.Wt2[4] = WtB + 3 * 1048576; g1.bias2[4] = (const float*)d_in[9];
    g1.dst[4] = nullptr; g1.splus[4] = 0; g1.fused[4] = 1;
    gemm_splitk<<<dim3(16, 4, 5), 256, 0, stream>>>(g1);

    attn_v7<<<dim3(16, 16), 512, 0, stream>>>(Proj,
                                              Proj + 262144,
                                              Gbf, cvec,
                                              Proj + 4 * 262144,
                                              Proj + 5 * 262144,
                                              Obf_mu, Obf_var);

    // K3: output projections -> d_out
    GemmArgs g3 = {};
    g3.Gbf = Gbf; g3.cvec = cvec;
    g3.A[0] = Obf_mu;  g3.Wt[0] = WtB + 6 * 1048576; g3.bias[0] = (const float*)d_in[15];
    g3.dst[0] = (float*)d_out;            g3.splus[0] = 0; g3.fused[0] = 0;
    g3.A[1] = Obf_var; g3.Wt[1] = WtB + 7 * 1048576; g3.bias[1] = (const float*)d_in[17];
    g3.dst[1] = (float*)d_out + 262144;   g3.splus[1] = 1; g3.fused[1] = 0;
    gemm_splitk<<<dim3(16, 4, 2), 256, 0, stream>>>(g3);
}